// Round 3
// baseline (528.874 us; speedup 1.0000x reference)
//
#include <hip/hip_runtime.h>

#define KG_E   200000
#define IN_DIM 256
#define OUT_DIM 128
#define BATCH  20000
#define NEDGE  640000

typedef unsigned short ushort_t;
typedef __attribute__((ext_vector_type(8))) short bf16x8;   // 8 bf16 = 4 VGPRs
typedef __attribute__((ext_vector_type(4))) float f32x4;

__device__ __forceinline__ float bf2f(unsigned int u) {
  return __builtin_bit_cast(float, u << 16);
}
__device__ __forceinline__ unsigned short f2bf(float f) {
  unsigned int x = __builtin_bit_cast(unsigned int, f);
  x += 0x7FFFu + ((x >> 16) & 1u);   // round-to-nearest-even
  return (unsigned short)(x >> 16);
}
// flags[0]=1 if float inputs are fp32 (else bf16); flags[1]=1 if ints are int64
__device__ __forceinline__ int idx_at(const void* p, long long i, int is64) {
  return is64 ? (int)((const long long*)p)[i] : ((const int*)p)[i];
}
__device__ __forceinline__ float fld(const void* p, int i, int isf32) {
  return isf32 ? ((const float*)p)[i] : bf2f(((const ushort_t*)p)[i]);
}

// ---------------------------------------------------------------------------
// D0: dtype detection, lane-parallel (one wave). ent ~ N(0,1): even-index
// ushorts of true-bf16 data have sane exponents; low halves of fp32 are junk.
// Odd int32 words of an int64 index array are all zero.
// ---------------------------------------------------------------------------
__global__ __launch_bounds__(64) void detect_kernel(const void* __restrict__ ent,
                                                    const void* __restrict__ edge,
                                                    int* __restrict__ flags) {
  int lane = threadIdx.x;                        // 64 lanes
  const ushort_t* u = (const ushort_t*)ent;
  int plaus = 0;
#pragma unroll
  for (int i = 0; i < 4; i++) {
    int e = (u[2 * (lane * 4 + i)] >> 7) & 0xff; // bf16 exponent field
    if (e >= 113 && e <= 141) plaus++;           // |x| in ~[2^-14, 2^14]
  }
  const int* ei = (const int*)edge;
  int nz = (ei[2 * lane + 1] != 0) ? 1 : 0;
#pragma unroll
  for (int m = 32; m >= 1; m >>= 1) {
    plaus += __shfl_xor(plaus, m);
    nz    += __shfl_xor(nz, m);
  }
  if (lane == 0) {
    flags[0] = (plaus >= 128) ? 0 : 1;           // 0 = bf16, 1 = fp32
    flags[1] = (nz == 0) ? 1 : 0;                // 1 = int64, 0 = int32
  }
}

// ---------------------------------------------------------------------------
// K1: gat[KG_E,128] (bf16) = ent[KG_E,256] @ W[128,256]^T + b
// 128x128 tile, BK=64, 4 waves, MFMA 16x16x32 bf16, fp32 accum.
// LDS: blocks of (16 rows x 8 k) bf16 = 256B at (rg*8+kq)*256; row li stored
// in slot li^kq (XOR swizzle). Staging lanes k-fast -> coalesced loads;
// fp32 path converts to bf16 inline.
// ---------------------------------------------------------------------------
__global__ __launch_bounds__(256) void gemm_kernel(
    const void* __restrict__ ent, const void* __restrict__ W,
    const void* __restrict__ bias, const int* __restrict__ flags,
    ushort_t* __restrict__ gat)
{
  __shared__ __align__(16) unsigned char lds[32768];  // A 16KB | B 16KB
  const int isf32 = flags[0];
  const int tid  = threadIdx.x;
  const int lane = tid & 63;
  const int w    = tid >> 6;
  const int m0   = blockIdx.x * 128;
  const int l16  = lane & 15;
  const int quad = lane >> 4;

  f32x4 acc[2][8];
#pragma unroll
  for (int i = 0; i < 2; i++)
#pragma unroll
    for (int j = 0; j < 8; j++) acc[i][j] = (f32x4){0.f, 0.f, 0.f, 0.f};

  for (int kb = 0; kb < IN_DIM; kb += 64) {
#pragma unroll
    for (int i = 0; i < 4; i++) {
      int idx = i * 256 + tid;        // 0..1023
      int r   = idx >> 3;             // tile row 0..127
      int kq  = idx & 7;              // k-octet 0..7
      int rg  = r >> 4, li = r & 15;
      int slot = li ^ kq;
      int gr = m0 + r; gr = gr < KG_E ? gr : (KG_E - 1);
      bf16x8 va, vb;
      if (isf32) {
        const float* ap = (const float*)ent + (size_t)gr * IN_DIM + kb + kq * 8;
        const float* bp = (const float*)W   + (size_t)r  * IN_DIM + kb + kq * 8;
        f32x4 a0 = *(const f32x4*)ap, a1 = *(const f32x4*)(ap + 4);
        f32x4 b0 = *(const f32x4*)bp, b1 = *(const f32x4*)(bp + 4);
#pragma unroll
        for (int j = 0; j < 4; j++) {
          ((short*)&va)[j]     = (short)f2bf(a0[j]);
          ((short*)&va)[4 + j] = (short)f2bf(a1[j]);
          ((short*)&vb)[j]     = (short)f2bf(b0[j]);
          ((short*)&vb)[4 + j] = (short)f2bf(b1[j]);
        }
      } else {
        va = *(const bf16x8*)((const ushort_t*)ent + (size_t)gr * IN_DIM + kb + kq * 8);
        vb = *(const bf16x8*)((const ushort_t*)W   + (size_t)r  * IN_DIM + kb + kq * 8);
      }
      *(bf16x8*)(lds + (rg * 8 + kq) * 256 + slot * 16) = va;
      *(bf16x8*)(lds + 16384 + (rg * 8 + kq) * 256 + slot * 16) = vb;
    }
    __syncthreads();
#pragma unroll
    for (int ks = 0; ks < 64; ks += 32) {
      int kq = (ks >> 3) + quad;
      bf16x8 a[2], b[8];
#pragma unroll
      for (int mt = 0; mt < 2; mt++)
        a[mt] = *(const bf16x8*)(lds + ((2 * w + mt) * 8 + kq) * 256 + (l16 ^ kq) * 16);
#pragma unroll
      for (int nt = 0; nt < 8; nt++)
        b[nt] = *(const bf16x8*)(lds + 16384 + (nt * 8 + kq) * 256 + (l16 ^ kq) * 16);
#pragma unroll
      for (int mt = 0; mt < 2; mt++)
#pragma unroll
        for (int nt = 0; nt < 8; nt++)
          acc[mt][nt] = __builtin_amdgcn_mfma_f32_16x16x32_bf16(
              a[mt], b[nt], acc[mt][nt], 0, 0, 0);
    }
    __syncthreads();
  }
  // epilogue: C/D layout col=lane&15, row=quad*4+reg (m89/m91 verified)
#pragma unroll
  for (int mt = 0; mt < 2; mt++) {
    int rbase = m0 + w * 32 + mt * 16 + quad * 4;
#pragma unroll
    for (int nt = 0; nt < 8; nt++) {
      int c = nt * 16 + l16;
      float bv = fld(bias, c, isf32);
#pragma unroll
      for (int reg = 0; reg < 4; reg++) {
        int r = rbase + reg;
        if (r < KG_E) gat[(size_t)r * OUT_DIM + c] = f2bf(acc[mt][nt][reg] + bv);
      }
    }
  }
}

// ---------------------------------------------------------------------------
// K2: per-node attention scalars. One wave per node/batch-row.
// ---------------------------------------------------------------------------
__global__ __launch_bounds__(256) void scores_kernel(
    const ushort_t* __restrict__ gat, const void* __restrict__ w_atten,
    const void* __restrict__ batch_ids, const int* __restrict__ flags,
    float* __restrict__ sR, float* __restrict__ sL)
{
  int isf32 = flags[0], is64 = flags[1];
  int wid  = blockIdx.x * 4 + (threadIdx.x >> 6);
  int lane = threadIdx.x & 63;
  bool isR = wid < KG_E;
  int node, woff;
  if (isR) { node = wid; woff = OUT_DIM; }
  else     { node = idx_at(batch_ids, wid - KG_E, is64); woff = 0; }
  node = node < 0 ? 0 : (node >= KG_E ? KG_E - 1 : node);
  unsigned int gp = *(const unsigned int*)(gat + (size_t)node * OUT_DIM + 2 * lane);
  float w0 = fld(w_atten, woff + 2 * lane, isf32);
  float w1 = fld(w_atten, woff + 2 * lane + 1, isf32);
  float p = bf2f(gp & 0xffffu) * w0 + bf2f(gp >> 16) * w1;
#pragma unroll
  for (int m = 32; m >= 1; m >>= 1) p += __shfl_xor(p, m);
  if (lane == 0) { if (isR) sR[wid] = p; else sL[wid - KG_E] = p; }
}

// ---------------------------------------------------------------------------
// CSR build: histogram -> scan -> scatter permutation
// ---------------------------------------------------------------------------
__global__ __launch_bounds__(256) void hist_kernel(const void* __restrict__ edge,
                                                   const int* __restrict__ flags,
                                                   int* __restrict__ counts)
{
  int is64 = flags[1];
  int e = blockIdx.x * 256 + threadIdx.x;
  if (e < NEDGE) {
    int r = idx_at(edge, e, is64);
    r = r < 0 ? 0 : (r >= BATCH ? BATCH - 1 : r);
    atomicAdd(&counts[r], 1);
  }
}

__global__ __launch_bounds__(1024) void scan_kernel(const int* __restrict__ counts,
                                                    int* __restrict__ offsets,
                                                    int* __restrict__ cursor)
{
  __shared__ int buf[1024];
  int running = 0;
  for (int base = 0; base < BATCH; base += 1024) {
    int i = base + (int)threadIdx.x;
    int v = (i < BATCH) ? counts[i] : 0;
    buf[threadIdx.x] = v;
    __syncthreads();
    for (int off = 1; off < 1024; off <<= 1) {
      int t = (threadIdx.x >= (unsigned)off) ? buf[threadIdx.x - off] : 0;
      __syncthreads();
      buf[threadIdx.x] += t;
      __syncthreads();
    }
    int incl = buf[threadIdx.x];
    if (i < BATCH) { int ex = running + incl - v; offsets[i] = ex; cursor[i] = ex; }
    int total = buf[1023];
    __syncthreads();
    running += total;
  }
  if (threadIdx.x == 0) offsets[BATCH] = running;
}

__global__ __launch_bounds__(256) void scatter_kernel(const void* __restrict__ edge,
                                                      const int* __restrict__ flags,
                                                      int* __restrict__ cursor,
                                                      int* __restrict__ perm)
{
  int is64 = flags[1];
  int e = blockIdx.x * 256 + threadIdx.x;
  if (e < NEDGE) {
    int r = idx_at(edge, e, is64);
    r = r < 0 ? 0 : (r >= BATCH ? BATCH - 1 : r);
    int p = atomicAdd(&cursor[r], 1);
    perm[p] = e;
  }
}

// ---------------------------------------------------------------------------
// K3: one wave per batch row. 64-edge chunks: lane-parallel att compute,
// shfl-broadcast, 64-lane coalesced gather of one 256B gat row per edge.
// Output is fp32 (reference output dtype): float2 per lane, coalesced.
// ---------------------------------------------------------------------------
__global__ __launch_bounds__(256) void aggregate_kernel(
    const ushort_t* __restrict__ gat, const void* __restrict__ edge,
    const int* __restrict__ perm, const int* __restrict__ offsets,
    const float* __restrict__ sR, const float* __restrict__ sL,
    const void* __restrict__ prelu, const int* __restrict__ flags,
    float* __restrict__ out)
{
  int isf32 = flags[0], is64 = flags[1];
  int row  = blockIdx.x * 4 + (threadIdx.x >> 6);
  int lane = threadIdx.x & 63;
  int beg = offsets[row], end = offsets[row + 1];
  float sLi = sL[row];
  float acc0 = 0.f, acc1 = 0.f, rowsum = 0.f;
  for (int base = beg; base < end; base += 64) {
    int n = end - base; n = n < 64 ? n : 64;
    float att_l = 0.f;
    int col_l = 0;
    if (base + lane < end) {
      int e = perm[base + lane];
      int c = idx_at(edge, (long long)NEDGE + e, is64);
      col_l = c < 0 ? 0 : (c >= KG_E ? KG_E - 1 : c);
      float score = sLi + sR[col_l];
      float lr = score > 0.f ? score : 0.2f * score;
      lr = lr > 80.f ? 80.f : (lr < -80.f ? -80.f : lr);
      att_l = __expf(-lr);
    }
    for (int j = 0; j < n; ++j) {
      float att = __shfl(att_l, j);
      int col   = __shfl(col_l, j);
      unsigned int pk = *(const unsigned int*)(gat + (size_t)col * OUT_DIM + 2 * lane);
      acc0 += att * bf2f(pk & 0xffffu);
      acc1 += att * bf2f(pk >> 16);
      rowsum += att;
    }
  }
  float inv = rowsum > 0.f ? 1.0f / rowsum : 0.f;
  float pw = fld(prelu, 0, isf32);
  float v0 = acc0 * inv, v1 = acc1 * inv;
  v0 = v0 >= 0.f ? v0 : pw * v0;
  v1 = v1 >= 0.f ? v1 : pw * v1;
  float2 o = make_float2(v0, v1);
  *(float2*)(out + (size_t)row * OUT_DIM + 2 * lane) = o;
}

// ---------------------------------------------------------------------------
extern "C" void kernel_launch(void* const* d_in, const int* in_sizes, int n_in,
                              void* d_out, int out_size, void* d_ws, size_t ws_size,
                              hipStream_t stream) {
  const void* ent       = d_in[0];   // [KG_E,256] fp32 (detected)
  const void* batch_ids = d_in[1];   // [B] int32 or int64 (detected)
  const void* edge      = d_in[2];   // [2,E] rows|cols
  const void* W         = d_in[3];   // [128,256]
  const void* bias      = d_in[4];   // [128]
  const void* w_atten   = d_in[5];   // [256]
  const void* prelu     = d_in[6];   // [1]
  float*      out       = (float*)d_out;   // [B,128] fp32

  char* p = (char*)d_ws;
  int* flags    = (int*)p;       p += 16;
  ushort_t* gat = (ushort_t*)p;  p += (size_t)KG_E * OUT_DIM * 2;  // 51.2 MB
  float* sR     = (float*)p;     p += (size_t)KG_E * 4;
  float* sL     = (float*)p;     p += (size_t)BATCH * 4;
  int* counts   = (int*)p;       p += (size_t)BATCH * 4;
  int* offsets  = (int*)p;       p += (size_t)(BATCH + 1) * 4;
  int* cursor   = (int*)p;       p += (size_t)BATCH * 4;
  int* perm     = (int*)p;       p += (size_t)NEDGE * 4;           // 2.56 MB

  hipMemsetAsync(counts, 0, BATCH * sizeof(int), stream);
  detect_kernel<<<dim3(1), dim3(64), 0, stream>>>(ent, edge, flags);
  gemm_kernel<<<dim3((KG_E + 127) / 128), dim3(256), 0, stream>>>(ent, W, bias, flags, gat);
  scores_kernel<<<dim3((KG_E + BATCH) / 4), dim3(256), 0, stream>>>(gat, w_atten, batch_ids, flags, sR, sL);
  hist_kernel<<<dim3(NEDGE / 256), dim3(256), 0, stream>>>(edge, flags, counts);
  scan_kernel<<<dim3(1), dim3(1024), 0, stream>>>(counts, offsets, cursor);
  scatter_kernel<<<dim3(NEDGE / 256), dim3(256), 0, stream>>>(edge, flags, cursor, perm);
  aggregate_kernel<<<dim3(BATCH / 4), dim3(256), 0, stream>>>(gat, edge, perm, offsets, sR, sL, prelu, flags, out);
}

// Round 4
// 436.679 us; speedup vs baseline: 1.2111x; 1.2111x over previous
//
#include <hip/hip_runtime.h>

#define KG_E   200000
#define IN_DIM 256
#define OUT_DIM 128
#define BATCH  20000
#define NEDGE  640000

typedef unsigned short ushort_t;
typedef __attribute__((ext_vector_type(8))) short bf16x8;   // 8 bf16 = 4 VGPRs
typedef __attribute__((ext_vector_type(4))) float f32x4;

__device__ __forceinline__ float bf2f(unsigned int u) {
  return __builtin_bit_cast(float, u << 16);
}
__device__ __forceinline__ unsigned short f2bf(float f) {
  unsigned int x = __builtin_bit_cast(unsigned int, f);
  x += 0x7FFFu + ((x >> 16) & 1u);   // round-to-nearest-even
  return (unsigned short)(x >> 16);
}
__device__ __forceinline__ int idx_at(const void* p, long long i, int is64) {
  return is64 ? (int)((const long long*)p)[i] : ((const int*)p)[i];
}
__device__ __forceinline__ float fld(const void* p, int i, int isf32) {
  return isf32 ? ((const float*)p)[i] : bf2f(((const ushort_t*)p)[i]);
}
__device__ __forceinline__ bf16x8 pack8(f32x4 a, f32x4 b) {
  bf16x8 r;
#pragma unroll
  for (int j = 0; j < 4; j++) {
    ((ushort_t*)&r)[j]     = f2bf(a[j]);
    ((ushort_t*)&r)[4 + j] = f2bf(b[j]);
  }
  return r;
}

// ---------------------------------------------------------------------------
// D0: dtype detection (one wave). flags[0]: 1=fp32 floats; flags[1]: 1=int64.
// ---------------------------------------------------------------------------
__global__ __launch_bounds__(64) void detect_kernel(const void* __restrict__ ent,
                                                    const void* __restrict__ edge,
                                                    int* __restrict__ flags) {
  int lane = threadIdx.x;
  const ushort_t* u = (const ushort_t*)ent;
  int plaus = 0;
#pragma unroll
  for (int i = 0; i < 4; i++) {
    int e = (u[2 * (lane * 4 + i)] >> 7) & 0xff;
    if (e >= 113 && e <= 141) plaus++;
  }
  const int* ei = (const int*)edge;
  int nz = (ei[2 * lane + 1] != 0) ? 1 : 0;
#pragma unroll
  for (int m = 32; m >= 1; m >>= 1) {
    plaus += __shfl_xor(plaus, m);
    nz    += __shfl_xor(nz, m);
  }
  if (lane == 0) {
    flags[0] = (plaus >= 128) ? 0 : 1;
    flags[1] = (nz == 0) ? 1 : 0;
  }
}

// ---------------------------------------------------------------------------
// K1: streaming GEMM, barrier-free K-loop.
// Block 512 thr (8 waves). W staged ONCE to LDS as bf16, swizzled
// (row*512 + (slot^ (row&15))*16). Each wave: 16 rows x 128 cols, K=256 in
// 8 MFMA steps; A global->reg with 4-deep ring prefetch. Epilogue computes
// sRn/sLn (fused scores), then LDS-transpose (stride 272) for coalesced
// 16B gat stores.
// ---------------------------------------------------------------------------
__global__ __launch_bounds__(512, 4) void gemm_kernel(
    const void* __restrict__ ent, const void* __restrict__ W,
    const void* __restrict__ bias, const void* __restrict__ w_atten,
    const int* __restrict__ flags, ushort_t* __restrict__ gat,
    float* __restrict__ sRn, float* __restrict__ sLn)
{
  __shared__ __align__(16) unsigned char lds[65536];
  const int isf32 = flags[0];
  const int tid  = threadIdx.x;
  const int lane = tid & 63;
  const int w    = tid >> 6;       // wave 0..7
  const int l16  = lane & 15;
  const int quad = lane >> 4;
  const int m0   = blockIdx.x * 128;

  // ---- stage W (128x256) -> LDS bf16, swizzled ----
#pragma unroll
  for (int i = 0; i < 8; i++) {
    int L = i * 512 + tid;              // 16B-slot id, 0..4095
    int r = L >> 5, s = L & 31;
    bf16x8 v;
    if (isf32) {
      const float* bp = (const float*)W + r * 256 + s * 8;
      v = pack8(*(const f32x4*)bp, *(const f32x4*)(bp + 4));
    } else {
      v = *(const bf16x8*)((const ushort_t*)W + r * 256 + s * 8);
    }
    *(bf16x8*)(lds + r * 512 + ((s ^ (r & 15)) * 16)) = v;
  }
  __syncthreads();

  const int row0 = m0 + w * 16;
  int arow = row0 + l16; arow = arow < KG_E ? arow : (KG_E - 1);

  f32x4 acc[8];
#pragma unroll
  for (int nt = 0; nt < 8; nt++) acc[nt] = (f32x4){0.f, 0.f, 0.f, 0.f};

#define MFMA_STEP(AF, KS)                                                     \
  do {                                                                        \
    _Pragma("unroll") for (int nt = 0; nt < 8; nt++) {                        \
      bf16x8 bf = *(const bf16x8*)(lds + (nt * 16 + l16) * 512 +              \
                                   ((((KS) * 4 + quad) ^ l16) * 16));         \
      acc[nt] = __builtin_amdgcn_mfma_f32_16x16x32_bf16(AF, bf, acc[nt], 0, 0, 0); \
    }                                                                         \
  } while (0)

  if (isf32) {
    const float* ap = (const float*)ent + (size_t)arow * IN_DIM + quad * 8;
    f32x4 b0[4], b1[4];
#pragma unroll
    for (int p = 0; p < 4; p++) {
      b0[p] = *(const f32x4*)(ap + p * 32);
      b1[p] = *(const f32x4*)(ap + p * 32 + 4);
    }
#pragma unroll
    for (int ks = 0; ks < 8; ks++) {
      bf16x8 af = pack8(b0[ks & 3], b1[ks & 3]);
      if (ks < 4) {
        b0[ks & 3] = *(const f32x4*)(ap + (ks + 4) * 32);
        b1[ks & 3] = *(const f32x4*)(ap + (ks + 4) * 32 + 4);
      }
      MFMA_STEP(af, ks);
    }
  } else {
    const ushort_t* ap = (const ushort_t*)ent + (size_t)arow * IN_DIM + quad * 8;
    bf16x8 ab[4];
#pragma unroll
    for (int p = 0; p < 4; p++) ab[p] = *(const bf16x8*)(ap + p * 32);
#pragma unroll
    for (int ks = 0; ks < 8; ks++) {
      bf16x8 af = ab[ks & 3];
      if (ks < 4) ab[ks & 3] = *(const bf16x8*)(ap + (ks + 4) * 32);
      MFMA_STEP(af, ks);
    }
  }
#undef MFMA_STEP

  // ---- epilogue: bias + fused per-node scores ----
  float bv[8], w1v[8], w2v[8];
#pragma unroll
  for (int nt = 0; nt < 8; nt++) {
    int c = nt * 16 + l16;
    bv[nt]  = fld(bias, c, isf32);
    w1v[nt] = fld(w_atten, c, isf32);
    w2v[nt] = fld(w_atten, OUT_DIM + c, isf32);
  }
  float pr[4] = {0.f, 0.f, 0.f, 0.f}, pl[4] = {0.f, 0.f, 0.f, 0.f};
#pragma unroll
  for (int nt = 0; nt < 8; nt++)
#pragma unroll
    for (int reg = 0; reg < 4; reg++) {
      float v = acc[nt][reg] + bv[nt];
      acc[nt][reg] = v;
      pr[reg] += v * w2v[nt];
      pl[reg] += v * w1v[nt];
    }
#pragma unroll
  for (int m = 1; m < 16; m <<= 1)
#pragma unroll
    for (int reg = 0; reg < 4; reg++) {
      pr[reg] += __shfl_xor(pr[reg], m);
      pl[reg] += __shfl_xor(pl[reg], m);
    }
  if (l16 == 0) {
#pragma unroll
    for (int reg = 0; reg < 4; reg++) {
      int r = row0 + quad * 4 + reg;
      if (r < KG_E) { sRn[r] = pr[reg]; sLn[r] = pl[reg]; }
    }
  }

  // ---- LDS transpose (reuse W region; stride 272B) + coalesced store ----
  __syncthreads();
#pragma unroll
  for (int nt = 0; nt < 8; nt++)
#pragma unroll
    for (int reg = 0; reg < 4; reg++)
      *(ushort_t*)(lds + (w * 16 + quad * 4 + reg) * 272 + (nt * 16 + l16) * 2) =
          f2bf(acc[nt][reg]);
  __syncthreads();
#pragma unroll
  for (int i = 0; i < 4; i++) {
    int L = i * 512 + tid;               // 16B units of block's 32KB output
    int rl = L >> 4, cs = L & 15;
    int gr = m0 + rl;
    if (gr < KG_E) {
      f32x4 v = *(const f32x4*)(lds + rl * 272 + cs * 16);
      *(f32x4*)((char*)gat + (size_t)gr * 256 + cs * 16) = v;
    }
  }
}

// ---------------------------------------------------------------------------
// CSR build: histogram -> 3-stage scan -> scatter
// ---------------------------------------------------------------------------
__global__ __launch_bounds__(256) void hist_kernel(const void* __restrict__ edge,
                                                   const int* __restrict__ flags,
                                                   int* __restrict__ counts)
{
  int is64 = flags[1];
  int e = blockIdx.x * 256 + threadIdx.x;
  if (e < NEDGE) {
    int r = idx_at(edge, e, is64);
    r = r < 0 ? 0 : (r >= BATCH ? BATCH - 1 : r);
    atomicAdd(&counts[r], 1);
  }
}

__global__ __launch_bounds__(1024) void scan1_kernel(const int* __restrict__ counts,
                                                     int* __restrict__ offsets,
                                                     int* __restrict__ blocksums)
{
  __shared__ int buf[1024];
  int i = blockIdx.x * 1024 + threadIdx.x;
  int v = (i < BATCH) ? counts[i] : 0;
  buf[threadIdx.x] = v;
  __syncthreads();
  for (int off = 1; off < 1024; off <<= 1) {
    int t = (threadIdx.x >= (unsigned)off) ? buf[threadIdx.x - off] : 0;
    __syncthreads();
    buf[threadIdx.x] += t;
    __syncthreads();
  }
  if (i < BATCH) offsets[i] = buf[threadIdx.x] - v;   // block-local exclusive
  if (threadIdx.x == 1023) blocksums[blockIdx.x] = buf[1023];
}

__global__ __launch_bounds__(64) void scan2_kernel(const int* __restrict__ blocksums,
                                                   int* __restrict__ blockoff,
                                                   int* __restrict__ offsets)
{
  int lane = threadIdx.x;
  int v = (lane < 20) ? blocksums[lane] : 0;
  int orig = v;
#pragma unroll
  for (int off = 1; off < 32; off <<= 1) {
    int t = __shfl_up(v, off);
    if (lane >= off) v += t;
  }
  if (lane < 20) blockoff[lane] = v - orig;           // exclusive
  if (lane == 19) offsets[BATCH] = v;                 // grand total
}

__global__ __launch_bounds__(1024) void scan3_kernel(int* __restrict__ offsets,
                                                     const int* __restrict__ blockoff,
                                                     int* __restrict__ cursor)
{
  int i = blockIdx.x * 1024 + threadIdx.x;
  if (i < BATCH) {
    int o = offsets[i] + blockoff[blockIdx.x];
    offsets[i] = o;
    cursor[i] = o;
  }
}

__global__ __launch_bounds__(256) void scatter_kernel(const void* __restrict__ edge,
                                                      const int* __restrict__ flags,
                                                      int* __restrict__ cursor,
                                                      int* __restrict__ perm)
{
  int is64 = flags[1];
  int e = blockIdx.x * 256 + threadIdx.x;
  if (e < NEDGE) {
    int r = idx_at(edge, e, is64);
    r = r < 0 ? 0 : (r >= BATCH ? BATCH - 1 : r);
    int p = atomicAdd(&cursor[r], 1);
    perm[p] = e;
  }
}

// ---------------------------------------------------------------------------
// K3: one wave per batch row; 64-edge chunks, lane-parallel att, broadcast
// gather unrolled x4 for MLP (4 independent 256B row gathers in flight).
// ---------------------------------------------------------------------------
__global__ __launch_bounds__(256) void aggregate_kernel(
    const ushort_t* __restrict__ gat, const void* __restrict__ edge,
    const int* __restrict__ perm, const int* __restrict__ offsets,
    const float* __restrict__ sRn, const float* __restrict__ sLn,
    const void* __restrict__ batch_ids, const void* __restrict__ prelu,
    const int* __restrict__ flags, float* __restrict__ out)
{
  int isf32 = flags[0], is64 = flags[1];
  int row  = blockIdx.x * 4 + (threadIdx.x >> 6);
  int lane = threadIdx.x & 63;
  int beg = offsets[row], end = offsets[row + 1];
  int b = idx_at(batch_ids, row, is64);
  b = b < 0 ? 0 : (b >= KG_E ? KG_E - 1 : b);
  float sLi = sLn[b];
  float acc0 = 0.f, acc1 = 0.f, rowsum = 0.f;
  for (int base = beg; base < end; base += 64) {
    int n = end - base; n = n < 64 ? n : 64;
    float att_l = 0.f;
    int col_l = 0;
    if (base + lane < end) {
      int e = perm[base + lane];
      int c = idx_at(edge, (long long)NEDGE + e, is64);
      col_l = c < 0 ? 0 : (c >= KG_E ? KG_E - 1 : c);
      float score = sLi + sRn[col_l];
      float lr = score > 0.f ? score : 0.2f * score;
      lr = lr > 80.f ? 80.f : (lr < -80.f ? -80.f : lr);
      att_l = __expf(-lr);
    }
    int j = 0;
    for (; j + 4 <= n; j += 4) {
      float a0 = __shfl(att_l, j),     a1 = __shfl(att_l, j + 1);
      float a2 = __shfl(att_l, j + 2), a3 = __shfl(att_l, j + 3);
      int c0 = __shfl(col_l, j),     c1 = __shfl(col_l, j + 1);
      int c2 = __shfl(col_l, j + 2), c3 = __shfl(col_l, j + 3);
      unsigned int p0 = *(const unsigned int*)(gat + (size_t)c0 * OUT_DIM + 2 * lane);
      unsigned int p1 = *(const unsigned int*)(gat + (size_t)c1 * OUT_DIM + 2 * lane);
      unsigned int p2 = *(const unsigned int*)(gat + (size_t)c2 * OUT_DIM + 2 * lane);
      unsigned int p3 = *(const unsigned int*)(gat + (size_t)c3 * OUT_DIM + 2 * lane);
      acc0 += a0 * bf2f(p0 & 0xffffu) + a1 * bf2f(p1 & 0xffffu) +
              a2 * bf2f(p2 & 0xffffu) + a3 * bf2f(p3 & 0xffffu);
      acc1 += a0 * bf2f(p0 >> 16) + a1 * bf2f(p1 >> 16) +
              a2 * bf2f(p2 >> 16) + a3 * bf2f(p3 >> 16);
      rowsum += a0 + a1 + a2 + a3;
    }
    for (; j < n; ++j) {
      float att = __shfl(att_l, j);
      int col   = __shfl(col_l, j);
      unsigned int pk = *(const unsigned int*)(gat + (size_t)col * OUT_DIM + 2 * lane);
      acc0 += att * bf2f(pk & 0xffffu);
      acc1 += att * bf2f(pk >> 16);
      rowsum += att;
    }
  }
  float inv = rowsum > 0.f ? 1.0f / rowsum : 0.f;
  float pw = fld(prelu, 0, isf32);
  float v0 = acc0 * inv, v1 = acc1 * inv;
  v0 = v0 >= 0.f ? v0 : pw * v0;
  v1 = v1 >= 0.f ? v1 : pw * v1;
  *(float2*)(out + (size_t)row * OUT_DIM + 2 * lane) = make_float2(v0, v1);
}

// ---------------------------------------------------------------------------
extern "C" void kernel_launch(void* const* d_in, const int* in_sizes, int n_in,
                              void* d_out, int out_size, void* d_ws, size_t ws_size,
                              hipStream_t stream) {
  const void* ent       = d_in[0];
  const void* batch_ids = d_in[1];
  const void* edge      = d_in[2];
  const void* W         = d_in[3];
  const void* bias      = d_in[4];
  const void* w_atten   = d_in[5];
  const void* prelu     = d_in[6];
  float*      out       = (float*)d_out;

  char* p = (char*)d_ws;
  int* flags     = (int*)p;       p += 64;
  ushort_t* gat  = (ushort_t*)p;  p += (size_t)KG_E * OUT_DIM * 2;  // 51.2 MB
  float* sRn     = (float*)p;     p += (size_t)KG_E * 4;            // 800 KB
  float* sLn     = (float*)p;     p += (size_t)KG_E * 4;            // 800 KB
  int* counts    = (int*)p;       p += (size_t)BATCH * 4;
  int* offsets   = (int*)p;       p += (size_t)(BATCH + 1) * 4;
  int* cursor    = (int*)p;       p += (size_t)BATCH * 4;
  int* blocksums = (int*)p;       p += 64 * 4;
  int* blockoff  = (int*)p;       p += 64 * 4;
  int* perm      = (int*)p;       p += (size_t)NEDGE * 4;           // 2.56 MB

  hipMemsetAsync(counts, 0, BATCH * sizeof(int), stream);
  detect_kernel<<<dim3(1), dim3(64), 0, stream>>>(ent, edge, flags);
  gemm_kernel<<<dim3((KG_E + 127) / 128), dim3(512), 0, stream>>>(
      ent, W, bias, w_atten, flags, gat, sRn, sLn);
  hist_kernel<<<dim3(NEDGE / 256), dim3(256), 0, stream>>>(edge, flags, counts);
  scan1_kernel<<<dim3(20), dim3(1024), 0, stream>>>(counts, offsets, blocksums);
  scan2_kernel<<<dim3(1), dim3(64), 0, stream>>>(blocksums, blockoff, offsets);
  scan3_kernel<<<dim3(20), dim3(1024), 0, stream>>>(offsets, blockoff, cursor);
  scatter_kernel<<<dim3(NEDGE / 256), dim3(256), 0, stream>>>(edge, flags, cursor, perm);
  aggregate_kernel<<<dim3(BATCH / 4), dim3(256), 0, stream>>>(
      gat, edge, perm, offsets, sRn, sLn, batch_ids, prelu, flags, out);
}

// Round 5
// 431.020 us; speedup vs baseline: 1.2270x; 1.0131x over previous
//
#include <hip/hip_runtime.h>

#define KG_E   200000
#define IN_DIM 256
#define OUT_DIM 128
#define BATCH  20000
#define NEDGE  640000

typedef unsigned short ushort_t;
typedef __attribute__((ext_vector_type(8))) short bf16x8;   // 8 bf16 = 4 VGPRs
typedef __attribute__((ext_vector_type(4))) float f32x4;

__device__ __forceinline__ float bf2f(unsigned int u) {
  return __builtin_bit_cast(float, u << 16);
}
__device__ __forceinline__ unsigned short f2bf(float f) {
  unsigned int x = __builtin_bit_cast(unsigned int, f);
  x += 0x7FFFu + ((x >> 16) & 1u);   // round-to-nearest-even
  return (unsigned short)(x >> 16);
}
__device__ __forceinline__ int idx_at(const void* p, long long i, int is64) {
  return is64 ? (int)((const long long*)p)[i] : ((const int*)p)[i];
}
__device__ __forceinline__ float fld(const void* p, int i, int isf32) {
  return isf32 ? ((const float*)p)[i] : bf2f(((const ushort_t*)p)[i]);
}
__device__ __forceinline__ bf16x8 pack8(f32x4 a, f32x4 b) {
  bf16x8 r;
#pragma unroll
  for (int j = 0; j < 4; j++) {
    ((ushort_t*)&r)[j]     = f2bf(a[j]);
    ((ushort_t*)&r)[4 + j] = f2bf(b[j]);
  }
  return r;
}

// ---------------------------------------------------------------------------
// D0: dtype detection (one wave). flags[0]: 1=fp32 floats; flags[1]: 1=int64.
// ---------------------------------------------------------------------------
__global__ __launch_bounds__(64) void detect_kernel(const void* __restrict__ ent,
                                                    const void* __restrict__ edge,
                                                    int* __restrict__ flags) {
  int lane = threadIdx.x;
  const ushort_t* u = (const ushort_t*)ent;
  int plaus = 0;
#pragma unroll
  for (int i = 0; i < 4; i++) {
    int e = (u[2 * (lane * 4 + i)] >> 7) & 0xff;
    if (e >= 113 && e <= 141) plaus++;
  }
  const int* ei = (const int*)edge;
  int nz = (ei[2 * lane + 1] != 0) ? 1 : 0;
#pragma unroll
  for (int m = 32; m >= 1; m >>= 1) {
    plaus += __shfl_xor(plaus, m);
    nz    += __shfl_xor(nz, m);
  }
  if (lane == 0) {
    flags[0] = (plaus >= 128) ? 0 : 1;
    flags[1] = (nz == 0) ? 1 : 0;
  }
}

// ---------------------------------------------------------------------------
// K1: streaming GEMM, barrier-free K-loop (unchanged from round 4).
// 512 thr / 8 waves; W staged once to LDS (bf16, XOR-swizzled); each wave
// computes 16 rows x 128 cols with 4-deep A-register ring prefetch.
// Epilogue fuses per-node scores sRn/sLn, then LDS-transpose for 16B stores.
// ---------------------------------------------------------------------------
__global__ __launch_bounds__(512, 4) void gemm_kernel(
    const void* __restrict__ ent, const void* __restrict__ W,
    const void* __restrict__ bias, const void* __restrict__ w_atten,
    const int* __restrict__ flags, ushort_t* __restrict__ gat,
    float* __restrict__ sRn, float* __restrict__ sLn)
{
  __shared__ __align__(16) unsigned char lds[65536];
  const int isf32 = flags[0];
  const int tid  = threadIdx.x;
  const int lane = tid & 63;
  const int w    = tid >> 6;       // wave 0..7
  const int l16  = lane & 15;
  const int quad = lane >> 4;
  const int m0   = blockIdx.x * 128;

#pragma unroll
  for (int i = 0; i < 8; i++) {
    int L = i * 512 + tid;              // 16B-slot id, 0..4095
    int r = L >> 5, s = L & 31;
    bf16x8 v;
    if (isf32) {
      const float* bp = (const float*)W + r * 256 + s * 8;
      v = pack8(*(const f32x4*)bp, *(const f32x4*)(bp + 4));
    } else {
      v = *(const bf16x8*)((const ushort_t*)W + r * 256 + s * 8);
    }
    *(bf16x8*)(lds + r * 512 + ((s ^ (r & 15)) * 16)) = v;
  }
  __syncthreads();

  const int row0 = m0 + w * 16;
  int arow = row0 + l16; arow = arow < KG_E ? arow : (KG_E - 1);

  f32x4 acc[8];
#pragma unroll
  for (int nt = 0; nt < 8; nt++) acc[nt] = (f32x4){0.f, 0.f, 0.f, 0.f};

#define MFMA_STEP(AF, KS)                                                     \
  do {                                                                        \
    _Pragma("unroll") for (int nt = 0; nt < 8; nt++) {                        \
      bf16x8 bf = *(const bf16x8*)(lds + (nt * 16 + l16) * 512 +              \
                                   ((((KS) * 4 + quad) ^ l16) * 16));         \
      acc[nt] = __builtin_amdgcn_mfma_f32_16x16x32_bf16(AF, bf, acc[nt], 0, 0, 0); \
    }                                                                         \
  } while (0)

  if (isf32) {
    const float* ap = (const float*)ent + (size_t)arow * IN_DIM + quad * 8;
    f32x4 b0[4], b1[4];
#pragma unroll
    for (int p = 0; p < 4; p++) {
      b0[p] = *(const f32x4*)(ap + p * 32);
      b1[p] = *(const f32x4*)(ap + p * 32 + 4);
    }
#pragma unroll
    for (int ks = 0; ks < 8; ks++) {
      bf16x8 af = pack8(b0[ks & 3], b1[ks & 3]);
      if (ks < 4) {
        b0[ks & 3] = *(const f32x4*)(ap + (ks + 4) * 32);
        b1[ks & 3] = *(const f32x4*)(ap + (ks + 4) * 32 + 4);
      }
      MFMA_STEP(af, ks);
    }
  } else {
    const ushort_t* ap = (const ushort_t*)ent + (size_t)arow * IN_DIM + quad * 8;
    bf16x8 ab[4];
#pragma unroll
    for (int p = 0; p < 4; p++) ab[p] = *(const bf16x8*)(ap + p * 32);
#pragma unroll
    for (int ks = 0; ks < 8; ks++) {
      bf16x8 af = ab[ks & 3];
      if (ks < 4) ab[ks & 3] = *(const bf16x8*)(ap + (ks + 4) * 32);
      MFMA_STEP(af, ks);
    }
  }
#undef MFMA_STEP

  float bv[8], w1v[8], w2v[8];
#pragma unroll
  for (int nt = 0; nt < 8; nt++) {
    int c = nt * 16 + l16;
    bv[nt]  = fld(bias, c, isf32);
    w1v[nt] = fld(w_atten, c, isf32);
    w2v[nt] = fld(w_atten, OUT_DIM + c, isf32);
  }
  float pr[4] = {0.f, 0.f, 0.f, 0.f}, pl[4] = {0.f, 0.f, 0.f, 0.f};
#pragma unroll
  for (int nt = 0; nt < 8; nt++)
#pragma unroll
    for (int reg = 0; reg < 4; reg++) {
      float v = acc[nt][reg] + bv[nt];
      acc[nt][reg] = v;
      pr[reg] += v * w2v[nt];
      pl[reg] += v * w1v[nt];
    }
#pragma unroll
  for (int m = 1; m < 16; m <<= 1)
#pragma unroll
    for (int reg = 0; reg < 4; reg++) {
      pr[reg] += __shfl_xor(pr[reg], m);
      pl[reg] += __shfl_xor(pl[reg], m);
    }
  if (l16 == 0) {
#pragma unroll
    for (int reg = 0; reg < 4; reg++) {
      int r = row0 + quad * 4 + reg;
      if (r < KG_E) { sRn[r] = pr[reg]; sLn[r] = pl[reg]; }
    }
  }

  __syncthreads();
#pragma unroll
  for (int nt = 0; nt < 8; nt++)
#pragma unroll
    for (int reg = 0; reg < 4; reg++)
      *(ushort_t*)(lds + (w * 16 + quad * 4 + reg) * 272 + (nt * 16 + l16) * 2) =
          f2bf(acc[nt][reg]);
  __syncthreads();
#pragma unroll
  for (int i = 0; i < 4; i++) {
    int L = i * 512 + tid;
    int rl = L >> 4, cs = L & 15;
    int gr = m0 + rl;
    if (gr < KG_E) {
      f32x4 v = *(const f32x4*)(lds + rl * 272 + cs * 16);
      *(f32x4*)((char*)gat + (size_t)gr * 256 + cs * 16) = v;
    }
  }
}

// ---------------------------------------------------------------------------
// CSR build: histogram -> 3-stage scan (scan3 fuses sLrow) -> scatter+att
// ---------------------------------------------------------------------------
__global__ __launch_bounds__(256) void hist_kernel(const void* __restrict__ edge,
                                                   const int* __restrict__ flags,
                                                   int* __restrict__ counts)
{
  int is64 = flags[1];
  int e = blockIdx.x * 256 + threadIdx.x;
  if (e < NEDGE) {
    int r = idx_at(edge, e, is64);
    r = r < 0 ? 0 : (r >= BATCH ? BATCH - 1 : r);
    atomicAdd(&counts[r], 1);
  }
}

__global__ __launch_bounds__(1024) void scan1_kernel(const int* __restrict__ counts,
                                                     int* __restrict__ offsets,
                                                     int* __restrict__ blocksums)
{
  __shared__ int buf[1024];
  int i = blockIdx.x * 1024 + threadIdx.x;
  int v = (i < BATCH) ? counts[i] : 0;
  buf[threadIdx.x] = v;
  __syncthreads();
  for (int off = 1; off < 1024; off <<= 1) {
    int t = (threadIdx.x >= (unsigned)off) ? buf[threadIdx.x - off] : 0;
    __syncthreads();
    buf[threadIdx.x] += t;
    __syncthreads();
  }
  if (i < BATCH) offsets[i] = buf[threadIdx.x] - v;   // block-local exclusive
  if (threadIdx.x == 1023) blocksums[blockIdx.x] = buf[1023];
}

__global__ __launch_bounds__(64) void scan2_kernel(const int* __restrict__ blocksums,
                                                   int* __restrict__ blockoff,
                                                   int* __restrict__ offsets)
{
  int lane = threadIdx.x;
  int v = (lane < 20) ? blocksums[lane] : 0;
  int orig = v;
#pragma unroll
  for (int off = 1; off < 32; off <<= 1) {
    int t = __shfl_up(v, off);
    if (lane >= off) v += t;
  }
  if (lane < 20) blockoff[lane] = v - orig;           // exclusive
  if (lane == 19) offsets[BATCH] = v;                 // grand total
}

// scan3 + fused sLrow gather (sLrow[i] = sLn[batch_ids[i]])
__global__ __launch_bounds__(1024) void scan3_kernel(int* __restrict__ offsets,
                                                     const int* __restrict__ blockoff,
                                                     int* __restrict__ cursor,
                                                     const void* __restrict__ batch_ids,
                                                     const float* __restrict__ sLn,
                                                     const int* __restrict__ flags,
                                                     float* __restrict__ sLrow)
{
  int is64 = flags[1];
  int i = blockIdx.x * 1024 + threadIdx.x;
  if (i < BATCH) {
    int o = offsets[i] + blockoff[blockIdx.x];
    offsets[i] = o;
    cursor[i] = o;
    int b = idx_at(batch_ids, i, is64);
    b = b < 0 ? 0 : (b >= KG_E ? KG_E - 1 : b);
    sLrow[i] = sLn[b];
  }
}

// scatter + per-edge attention: colatt[p] = (col, att)
__global__ __launch_bounds__(256) void scatter_kernel(const void* __restrict__ edge,
                                                      const int* __restrict__ flags,
                                                      const float* __restrict__ sLrow,
                                                      const float* __restrict__ sRn,
                                                      int* __restrict__ cursor,
                                                      int2* __restrict__ colatt)
{
  int is64 = flags[1];
  int e = blockIdx.x * 256 + threadIdx.x;
  if (e < NEDGE) {
    int r = idx_at(edge, e, is64);
    r = r < 0 ? 0 : (r >= BATCH ? BATCH - 1 : r);
    int c = idx_at(edge, (long long)NEDGE + e, is64);
    c = c < 0 ? 0 : (c >= KG_E ? KG_E - 1 : c);
    float score = sLrow[r] + sRn[c];
    float lr = score > 0.f ? score : 0.2f * score;
    lr = lr > 80.f ? 80.f : (lr < -80.f ? -80.f : lr);
    float att = __expf(-lr);
    int p = atomicAdd(&cursor[r], 1);
    colatt[p] = make_int2(c, __builtin_bit_cast(int, att));
  }
}

// ---------------------------------------------------------------------------
// K3: one wave per batch row. Inner loop: wave-uniform s_load of (col,att)
// pairs (x4 unrolled) + 4 independent 256B row gathers + FMAs. No shfl.
// ---------------------------------------------------------------------------
__global__ __launch_bounds__(256) void aggregate_kernel(
    const ushort_t* __restrict__ gat, const int2* __restrict__ colatt,
    const int* __restrict__ offsets, const void* __restrict__ prelu,
    const int* __restrict__ flags, float* __restrict__ out)
{
  int isf32 = flags[0];
  int row  = __builtin_amdgcn_readfirstlane(blockIdx.x * 4 + (threadIdx.x >> 6));
  int lane = threadIdx.x & 63;
  int beg = __builtin_amdgcn_readfirstlane(offsets[row]);
  int end = __builtin_amdgcn_readfirstlane(offsets[row + 1]);
  float acc0 = 0.f, acc1 = 0.f, rowsum = 0.f;
  int j = beg;
  for (; j + 4 <= end; j += 4) {
    int2 q0 = colatt[j],     q1 = colatt[j + 1];
    int2 q2 = colatt[j + 2], q3 = colatt[j + 3];
    float a0 = __builtin_bit_cast(float, q0.y), a1 = __builtin_bit_cast(float, q1.y);
    float a2 = __builtin_bit_cast(float, q2.y), a3 = __builtin_bit_cast(float, q3.y);
    unsigned int p0 = *(const unsigned int*)(gat + (size_t)q0.x * OUT_DIM + 2 * lane);
    unsigned int p1 = *(const unsigned int*)(gat + (size_t)q1.x * OUT_DIM + 2 * lane);
    unsigned int p2 = *(const unsigned int*)(gat + (size_t)q2.x * OUT_DIM + 2 * lane);
    unsigned int p3 = *(const unsigned int*)(gat + (size_t)q3.x * OUT_DIM + 2 * lane);
    acc0 += a0 * bf2f(p0 & 0xffffu) + a1 * bf2f(p1 & 0xffffu) +
            a2 * bf2f(p2 & 0xffffu) + a3 * bf2f(p3 & 0xffffu);
    acc1 += a0 * bf2f(p0 >> 16) + a1 * bf2f(p1 >> 16) +
            a2 * bf2f(p2 >> 16) + a3 * bf2f(p3 >> 16);
    rowsum += a0 + a1 + a2 + a3;
  }
  for (; j < end; ++j) {
    int2 q = colatt[j];
    float a = __builtin_bit_cast(float, q.y);
    unsigned int pk = *(const unsigned int*)(gat + (size_t)q.x * OUT_DIM + 2 * lane);
    acc0 += a * bf2f(pk & 0xffffu);
    acc1 += a * bf2f(pk >> 16);
    rowsum += a;
  }
  float inv = rowsum > 0.f ? 1.0f / rowsum : 0.f;
  float pw = fld(prelu, 0, isf32);
  float v0 = acc0 * inv, v1 = acc1 * inv;
  v0 = v0 >= 0.f ? v0 : pw * v0;
  v1 = v1 >= 0.f ? v1 : pw * v1;
  *(float2*)(out + (size_t)row * OUT_DIM + 2 * lane) = make_float2(v0, v1);
}

// ---------------------------------------------------------------------------
extern "C" void kernel_launch(void* const* d_in, const int* in_sizes, int n_in,
                              void* d_out, int out_size, void* d_ws, size_t ws_size,
                              hipStream_t stream) {
  const void* ent       = d_in[0];
  const void* batch_ids = d_in[1];
  const void* edge      = d_in[2];
  const void* W         = d_in[3];
  const void* bias      = d_in[4];
  const void* w_atten   = d_in[5];
  const void* prelu     = d_in[6];
  float*      out       = (float*)d_out;

  char* p = (char*)d_ws;
  int* flags     = (int*)p;       p += 64;
  ushort_t* gat  = (ushort_t*)p;  p += (size_t)KG_E * OUT_DIM * 2;  // 51.2 MB
  float* sRn     = (float*)p;     p += (size_t)KG_E * 4;            // 800 KB
  float* sLn     = (float*)p;     p += (size_t)KG_E * 4;            // 800 KB
  float* sLrow   = (float*)p;     p += (size_t)BATCH * 4;
  int* counts    = (int*)p;       p += (size_t)BATCH * 4;
  int* offsets   = (int*)p;       p += (size_t)(BATCH + 1) * 4;
  int* cursor    = (int*)p;       p += (size_t)BATCH * 4;
  int* blocksums = (int*)p;       p += 64 * 4;
  int* blockoff  = (int*)p;       p += 64 * 4;
  p = (char*)(((size_t)p + 15) & ~(size_t)15);
  int2* colatt   = (int2*)p;      p += (size_t)NEDGE * 8;           // 5.1 MB

  hipMemsetAsync(counts, 0, BATCH * sizeof(int), stream);
  detect_kernel<<<dim3(1), dim3(64), 0, stream>>>(ent, edge, flags);
  gemm_kernel<<<dim3((KG_E + 127) / 128), dim3(512), 0, stream>>>(
      ent, W, bias, w_atten, flags, gat, sRn, sLn);
  hist_kernel<<<dim3(NEDGE / 256), dim3(256), 0, stream>>>(edge, flags, counts);
  scan1_kernel<<<dim3(20), dim3(1024), 0, stream>>>(counts, offsets, blocksums);
  scan2_kernel<<<dim3(1), dim3(64), 0, stream>>>(blocksums, blockoff, offsets);
  scan3_kernel<<<dim3(20), dim3(1024), 0, stream>>>(offsets, blockoff, cursor,
                                                    batch_ids, sLn, flags, sLrow);
  scatter_kernel<<<dim3(NEDGE / 256), dim3(256), 0, stream>>>(
      edge, flags, sLrow, sRn, cursor, colatt);
  aggregate_kernel<<<dim3(BATCH / 4), dim3(256), 0, stream>>>(
      gat, colatt, offsets, prelu, flags, out);
}